// Round 13
// baseline (201.834 us; speedup 1.0000x reference)
//
#include <hip/hip_runtime.h>
#include <stdint.h>

#define B_N 16384
#define H_N 256
#define IN_W 258
#define GX_N 70
#define GY_N 70
#define SW_N 2
#define KK_N 25

typedef __bf16 bf16x8 __attribute__((ext_vector_type(8)));
typedef __bf16 bf16x4 __attribute__((ext_vector_type(4)));
typedef __bf16 bf16x2 __attribute__((ext_vector_type(2)));
typedef float f32x4 __attribute__((ext_vector_type(4)));
typedef float f32x2 __attribute__((ext_vector_type(2)));

#define AS1 __attribute__((address_space(1)))
#define AS3 __attribute__((address_space(3)))

static __device__ __forceinline__ void gload16(const void* g, void* l) {
    __builtin_amdgcn_global_load_lds((const AS1 uint32_t*)g, (AS3 uint32_t*)l, 16, 0, 0);
}

// ---- ws layout (bf16 elements) ----
// AB    at 0        : [16384][512]  ([feat|hid])            16 MB
// wfull at 8388608  : [1024][512]   rows j=c*256+col, c in {r,i,s,n};
//                     k<256 -> wih[base_c+col][k], k>=256 -> whh[base_c+col][k-256]
//                     base_c = {0,256,768,512}
// woutB at 8912896  : [256][512]
// comb  at 9043968  : [16384][512]  ([mix|q])               16 MB
// ugsg  at 17432576 : [16384][256][2] (ug,sg interleaved)   16 MB
#define E_AB   8388608ULL
#define E_WF   8912896ULL
#define E_WOUT 9043968ULL
#define E_COMB 9043968ULL
#define E_UGSG 17432576ULL

// 16B-store cast: each thread converts 8 f32 -> bf16x8 per iteration.
// All section boundaries and k-splits are ==0 mod 8.
__global__ __launch_bounds__(256) void cast_kernel(
    const float* __restrict__ in_t, const float* __restrict__ hid,
    const float* __restrict__ wih, const float* __restrict__ whh,
    const float* __restrict__ wout, __bf16* __restrict__ dst)
{
    size_t g = (size_t)blockIdx.x * blockDim.x + threadIdx.x;
    size_t stride = (size_t)gridDim.x * blockDim.x;
    for (size_t e = g * 8; e < E_WOUT; e += stride * 8) {
        float s[8];
        if (e < E_AB) {
            size_t row = e >> 9;
            size_t c = e & 511;
            if (c < 256) {
                const f32x2* s2 = reinterpret_cast<const f32x2*>(in_t + row * IN_W + c);
#pragma unroll
                for (int q = 0; q < 4; q++) { f32x2 a = s2[q]; s[q * 2] = a.x; s[q * 2 + 1] = a.y; }
            } else {
                const f32x4* s4 = reinterpret_cast<const f32x4*>(hid + row * 256 + (c - 256));
#pragma unroll
                for (int q = 0; q < 2; q++) { f32x4 a = s4[q]; s[q*4]=a.x; s[q*4+1]=a.y; s[q*4+2]=a.z; s[q*4+3]=a.w; }
            }
        } else if (e < E_WF) {
            size_t off = e - E_AB;
            size_t j = off >> 9;       // 0..1023
            size_t k = off & 511;
            size_t c = j >> 8;         // 0..3
            size_t col = j & 255;
            size_t base = (c == 0) ? 0 : (c == 1) ? 256 : (c == 2) ? 768 : 512;
            const float* srcm = (k < 256) ? wih : whh;
            const f32x4* s4 = reinterpret_cast<const f32x4*>(srcm + (base + col) * 256 + (k & 255));
#pragma unroll
            for (int q = 0; q < 2; q++) { f32x4 a = s4[q]; s[q*4]=a.x; s[q*4+1]=a.y; s[q*4+2]=a.z; s[q*4+3]=a.w; }
        } else {
            const f32x4* s4 = reinterpret_cast<const f32x4*>(wout + (e - E_WF));
#pragma unroll
            for (int q = 0; q < 2; q++) { f32x4 a = s4[q]; s[q*4]=a.x; s[q*4+1]=a.y; s[q*4+2]=a.z; s[q*4+3]=a.w; }
        }
        bf16x8 o;
#pragma unroll
        for (int q = 0; q < 8; q++) o[q] = (__bf16)s[q];
        *reinterpret_cast<bf16x8*>(dst + e) = o;
    }
}

// Fused gates GEMM, K=512 concat form. r6-PROVEN 2-phase dbuf pipeline
// (46-48 us, VGPR 64, no spill). Counted-vmcnt variants regressed twice
// (r3/r7) — do not retry as graft.
// block = 128 rows x 128 cols (32 hcols x 4 gates), 4 waves, wave 32x128,
// acc 20 f32x4 = 80 regs. LDS 32KB -> 4 blocks/CU (grid 1024 = 4/CU).
__global__ __launch_bounds__(256, 2) void gates_gemm(
    const __bf16* __restrict__ AB, const __bf16* __restrict__ wfull,
    const float* __restrict__ b_ih, const float* __restrict__ b_hh,
    __bf16* __restrict__ comb, __bf16* __restrict__ ugsg)
{
    __shared__ __bf16 ldsA[2][4096];   // [buf][seg(4)][row(128)][8]
    __shared__ __bf16 ldsB[2][4096];   // [buf][seg(4)][brow(128)][8]
    const int t = threadIdx.x;
    const int lane = t & 63, w = t >> 6;
    const int lr = lane & 15, seg = lane >> 4;
    const int rb = blockIdx.x * 128;
    const int h0 = blockIdx.y * 32;

    // staging: thread t owns row (t&127), k-segs {t>>7, (t>>7)+2}
    const int rA = t & 127;
    const int sA = t >> 7;             // 0..1
    const __bf16* gAt = AB + (size_t)(rb + rA) * 512 + sA * 8;
    const int bc = rA >> 5, bcol = rA & 31;  // brow -> wfull row bc*256+h0+bcol
    const __bf16* gBt = wfull + (size_t)(bc * 256 + h0 + bcol) * 512 + sA * 8;
    __bf16* lA0 = &ldsA[0][t * 8];
    __bf16* lA1 = &ldsA[1][t * 8];
    __bf16* lB0 = &ldsB[0][t * 8];
    __bf16* lB1 = &ldsB[1][t * 8];

    f32x4 acc[2][6], accni[2][2], accnh[2][2];
#pragma unroll
    for (int rh = 0; rh < 2; rh++) {
#pragma unroll
        for (int cn = 0; cn < 6; cn++) acc[rh][cn] = (f32x4){0.f, 0.f, 0.f, 0.f};
        accni[rh][0] = (f32x4){0.f, 0.f, 0.f, 0.f};
        accni[rh][1] = (f32x4){0.f, 0.f, 0.f, 0.f};
        accnh[rh][0] = (f32x4){0.f, 0.f, 0.f, 0.f};
        accnh[rh][1] = (f32x4){0.f, 0.f, 0.f, 0.f};
    }

    // prologue: stage tile 0 into buf 0
    gload16(gAt + 0, lA0);
    gload16(gAt + 16, lA0 + 2048);
    gload16(gBt + 0, lB0);
    gload16(gBt + 16, lB0 + 2048);
    __syncthreads();   // implicit vmcnt(0)

#pragma unroll 1
    for (int tt = 0; tt < 16; tt++) {
        const int cur = tt & 1;
        if (tt < 15) {   // issue next tile's stage BEFORE compute
            const int kn = (tt + 1) * 32;
            __bf16* la = cur ? lA0 : lA1;
            __bf16* lb = cur ? lB0 : lB1;
            gload16(gAt + kn, la);
            gload16(gAt + kn + 16, la + 2048);
            gload16(gBt + kn, lb);
            gload16(gBt + kn + 16, lb + 2048);
        }
        const __bf16* cA = ldsA[cur];
        const __bf16* cB = ldsB[cur];
        bf16x8 af[2];
#pragma unroll
        for (int rh = 0; rh < 2; rh++)
            af[rh] = *reinterpret_cast<const bf16x8*>(cA + seg * 1024 + (w * 32 + rh * 16 + lr) * 8);
#pragma unroll
        for (int cn = 0; cn < 6; cn++) {
            const int c = cn >> 1, hh = cn & 1;
            bf16x8 bb = *reinterpret_cast<const bf16x8*>(cB + seg * 1024 + (c * 32 + hh * 16 + lr) * 8);
#pragma unroll
            for (int rh = 0; rh < 2; rh++)
                acc[rh][(c << 1) + hh] = __builtin_amdgcn_mfma_f32_16x16x32_bf16(af[rh], bb, acc[rh][(c << 1) + hh], 0, 0, 0);
        }
        bf16x8 b6 = *reinterpret_cast<const bf16x8*>(cB + seg * 1024 + (96 + lr) * 8);
        bf16x8 b7 = *reinterpret_cast<const bf16x8*>(cB + seg * 1024 + (112 + lr) * 8);
        if (tt < 8) {
#pragma unroll
            for (int rh = 0; rh < 2; rh++) {
                accni[rh][0] = __builtin_amdgcn_mfma_f32_16x16x32_bf16(af[rh], b6, accni[rh][0], 0, 0, 0);
                accni[rh][1] = __builtin_amdgcn_mfma_f32_16x16x32_bf16(af[rh], b7, accni[rh][1], 0, 0, 0);
            }
        } else {
#pragma unroll
            for (int rh = 0; rh < 2; rh++) {
                accnh[rh][0] = __builtin_amdgcn_mfma_f32_16x16x32_bf16(af[rh], b6, accnh[rh][0], 0, 0, 0);
                accnh[rh][1] = __builtin_amdgcn_mfma_f32_16x16x32_bf16(af[rh], b7, accnh[rh][1], 0, 0, 0);
            }
        }
        __syncthreads();   // vmcnt(0): next tile landed; lgkm: reads done
    }

#pragma unroll
    for (int hh = 0; hh < 2; hh++) {
        const int col = h0 + hh * 16 + lr;
        const float br_ = b_ih[col] + b_hh[col];
        const float bi_ = b_ih[col + 256] + b_hh[col + 256];
        const float bs_ = b_ih[col + 768] + b_hh[col + 768];
        const float bni = b_ih[col + 512];
        const float bnh = b_hh[col + 512];
#pragma unroll
        for (int rh = 0; rh < 2; rh++) {
#pragma unroll
            for (int r = 0; r < 4; r++) {
                const int row = rb + w * 32 + rh * 16 + seg * 4 + r;
                float sr = acc[rh][hh][r] + br_;
                float si = acc[rh][2 + hh][r] + bi_;
                float ss = acc[rh][4 + hh][r] + bs_;
                float vni = accni[rh][hh][r] + bni;
                float vnh = accnh[rh][hh][r] + bnh;
                float rg = 1.f / (1.f + __expf(-sr));
                float ug = 1.f / (1.f + __expf(-si));
                float sg = 1.f / (1.f + __expf(-ss));
                float ng = tanhf(vni + rg * vnh);
                comb[(size_t)row * 512 + 256 + col] = (__bf16)ng;
                bf16x2 us;
                us.x = (__bf16)ug;
                us.y = (__bf16)sg;
                *reinterpret_cast<bf16x2*>(ugsg + ((size_t)row * 256 + col) * 2) = us;
            }
        }
    }
}

// DPP 64-lane sum (6 VALU adds, zero DS-pipe ops). CTRL is a template
// param (must be an integer-constant expr). bound_ctrl=true: invalid
// source lane reads 0 (sum identity).
template <int CTRL>
static __device__ __forceinline__ float dpp_add_step(float x) {
    int xi = __builtin_bit_cast(int, x);
    int sh = __builtin_amdgcn_update_dpp(0, xi, CTRL, 0xf, 0xf, true);
    return x + __builtin_bit_cast(float, sh);
}
static __device__ __forceinline__ float wave_sum_readlane(float x) {
    x = dpp_add_step<0x111>(x);  // row_shr:1
    x = dpp_add_step<0x112>(x);  // row_shr:2
    x = dpp_add_step<0x114>(x);  // row_shr:4
    x = dpp_add_step<0x118>(x);  // row_shr:8  -> lane15/31/47/63 hold row sums
    x = dpp_add_step<0x142>(x);  // row_bcast:15
    x = dpp_add_step<0x143>(x);  // row_bcast:31 -> lane63 = total
    int s = __builtin_amdgcn_readlane(__builtin_bit_cast(int, x), 63);
    return __builtin_bit_cast(float, s);
}

// Attention v4: occupancy fix over r11's v3 (31.8us). v3 held v[25]
// f32x4 live across the kernel (~160 VGPR -> 3 waves/SIMD) so the 25
// L2-latency loads couldn't be hidden. v4 consumes each context vector
// immediately in the score phase and RELOADS it (L1/L2-hot) in the
// weighted-sum phase. The base pointer is laundered through an empty
// asm between phases so the compiler cannot CSE the reloads back into
// live-across values (memory is const -> it would otherwise). Target
// ~80 VGPR -> 6 waves/SIMD, 2x latency hiding.
__global__ __launch_bounds__(256) void attn_kernel(
    const float* __restrict__ in_t, const float* __restrict__ memory,
    __bf16* __restrict__ comb)
{
    const int w = threadIdx.x >> 6;
    const int lane = threadIdx.x & 63;
    const int b = blockIdx.x * 4 + w;
    const float* row_in = in_t + (size_t)b * IN_W;
    int gx = (int)row_in[256] + SW_N;
    int gy = (int)row_in[257] + SW_N;
    gx = min(max(gx, 0), GX_N - 1);
    gy = min(max(gy, 0), GY_N - 1);

    int xs[5], ys[5];
#pragma unroll
    for (int d = 0; d < 5; d++) {
        xs[d] = min(max(gx + d - SW_N, 0), GX_N - 1);
        ys[d] = min(max(gy + d - SW_N, 0), GY_N - 1);
    }

    bf16x4 qb = *reinterpret_cast<const bf16x4*>(comb + (size_t)b * 512 + 256 + lane * 4);
    const float q0 = (float)qb.x, q1 = (float)qb.y, q2 = (float)qb.z, q3 = (float)qb.w;

    float sc[KK_N];
#pragma unroll
    for (int k = 0; k < KK_N; k++) {       // full unroll: sc[] static-indexed
        const int i = k / 5, j = k % 5;    // compile-time
        const f32x4* cp = reinterpret_cast<const f32x4*>(
            memory + ((size_t)xs[i] * GY_N + ys[j]) * H_N);
        f32x4 v = cp[lane];                // coalesced 1KB/wave, consumed now
        float p = q0 * v.x + q1 * v.y + q2 * v.z + q3 * v.w;
        sc[k] = wave_sum_readlane(p);      // 6 VALU-DPP + readlane, no DS
    }

    // softmax over 25 uniform scores (ref: attn==0 -> -inf mask; all-masked -> 0)
#pragma unroll
    for (int k = 0; k < KK_N; k++) sc[k] = (sc[k] == 0.f) ? -INFINITY : sc[k];
    float mx = -INFINITY;
#pragma unroll
    for (int k = 0; k < KK_N; k++) mx = fmaxf(mx, sc[k]);
    float d = 0.f;
    if (mx > -INFINITY) {
#pragma unroll
        for (int k = 0; k < KK_N; k++) { sc[k] = __expf(sc[k] - mx); d += sc[k]; }
    } else {
#pragma unroll
        for (int k = 0; k < KK_N; k++) sc[k] = 0.f;
    }
    const float inv = (d != 0.f) ? 1.f / d : 0.f;

    // launder base pointer: block CSE with phase-1 loads (forces reload,
    // keeps VGPR count low instead of 25 live f32x4)
    uintptr_t mb = (uintptr_t)memory;
    asm volatile("" : "+v"(mb));
    const float* mem2 = (const float*)mb;

    f32x4 o = (f32x4){0.f, 0.f, 0.f, 0.f};
#pragma unroll
    for (int k = 0; k < KK_N; k++) {
        const int i = k / 5, j = k % 5;
        const f32x4* cp = reinterpret_cast<const f32x4*>(
            mem2 + ((size_t)xs[i] * GY_N + ys[j]) * H_N);
        f32x4 v = cp[lane];                // L1/L2-hot reload
        const float wk = sc[k] * inv;
        o.x += wk * v.x; o.y += wk * v.y; o.z += wk * v.z; o.w += wk * v.w;
    }
    bf16x4 ob;
    ob.x = (__bf16)o.x; ob.y = (__bf16)o.y; ob.z = (__bf16)o.z; ob.w = (__bf16)o.w;
    *reinterpret_cast<bf16x4*>(comb + (size_t)b * 512 + lane * 4) = ob;
}

// Output GEMM (K=512) + tanh + final blend. r0-exact single-buffered
// structure, (256,4): 12 KB LDS -> 4 blocks/CU at VGPR cap 64 (acc is
// only 32 regs — safe). Measured ≈ dbuf variant (r12 vs r11, within
// noise); kept for the higher blocks/CU.
__global__ __launch_bounds__(256, 4) void out_gemm(
    const __bf16* __restrict__ comb, const __bf16* __restrict__ woB,
    const float* __restrict__ b_out, const __bf16* __restrict__ ugsg,
    const float* __restrict__ hidden, float* __restrict__ out)
{
    __shared__ __bf16 ldsA[4096], ldsB[2048];
    const int t = threadIdx.x;
    const int lane = t & 63, w = t >> 6;
    const int lr = lane & 15, seg = lane >> 4;
    const int rb = blockIdx.x * 128;
    const int n0 = blockIdx.y * 64;

    const __bf16* gA = comb + (size_t)(rb + (t & 127)) * 512 + ((t >> 7) << 3);
    __bf16* lA = ldsA + t * 8;
    const __bf16* gB = woB + (size_t)(n0 + (t & 63)) * 512 + ((t >> 6) << 3);
    __bf16* lB = ldsB + t * 8;

    f32x4 acc[2][4];
#pragma unroll
    for (int rh = 0; rh < 2; rh++)
#pragma unroll
        for (int ct = 0; ct < 4; ct++) acc[rh][ct] = (f32x4){0.f, 0.f, 0.f, 0.f};

    for (int kt = 0; kt < 512; kt += 32) {
        gload16(gA + kt, lA);
        gload16(gA + kt + 16, lA + 2048);
        gload16(gB + kt, lB);
        __syncthreads();

        bf16x8 af[2];
#pragma unroll
        for (int rh = 0; rh < 2; rh++) {
            int tr = w * 32 + rh * 16 + lr;
            af[rh] = *reinterpret_cast<const bf16x8*>(ldsA + seg * 1024 + tr * 8);
        }
#pragma unroll
        for (int ct = 0; ct < 4; ct++) {
            bf16x8 bb = *reinterpret_cast<const bf16x8*>(ldsB + seg * 512 + (ct * 16 + lr) * 8);
#pragma unroll
            for (int rh = 0; rh < 2; rh++)
                acc[rh][ct] = __builtin_amdgcn_mfma_f32_16x16x32_bf16(af[rh], bb, acc[rh][ct], 0, 0, 0);
        }
        __syncthreads();
    }

#pragma unroll
    for (int ct = 0; ct < 4; ct++) {
        int col = n0 + ct * 16 + lr;
        float bo = b_out[col];
#pragma unroll
        for (int rh = 0; rh < 2; rh++) {
#pragma unroll
            for (int r = 0; r < 4; r++) {
                int row = rb + w * 32 + rh * 16 + seg * 4 + r;
                size_t idx = (size_t)row * 256 + col;
                float acs = tanhf(acc[rh][ct][r] + bo);
                float ng = (float)comb[(size_t)row * 512 + 256 + col];
                bf16x2 us = *reinterpret_cast<const bf16x2*>(ugsg + idx * 2);
                float ug = (float)us.x, sg = (float)us.y;
                float curr = ng + sg * acs;
                out[idx] = curr + ug * (hidden[idx] - curr);
            }
        }
    }
}

extern "C" void kernel_launch(void* const* d_in, const int* in_sizes, int n_in,
                              void* d_out, int out_size, void* d_ws, size_t ws_size,
                              hipStream_t stream) {
    const float* input_t = (const float*)d_in[0];
    const float* hidden  = (const float*)d_in[1];
    const float* w_ih    = (const float*)d_in[2];
    const float* b_ih    = (const float*)d_in[3];
    const float* w_hh    = (const float*)d_in[4];
    const float* b_hh    = (const float*)d_in[5];
    const float* w_out   = (const float*)d_in[6];
    const float* b_out   = (const float*)d_in[7];
    const float* memory  = (const float*)d_in[8];
    float* out = (float*)d_out;

    __bf16* base  = (__bf16*)d_ws;
    __bf16* AB    = base;
    __bf16* wfull = base + E_AB;
    __bf16* woutB = base + E_WF;
    __bf16* comb  = base + E_COMB;
    __bf16* ugsg  = base + E_UGSG;

    cast_kernel<<<4096, 256, 0, stream>>>(input_t, hidden, w_ih, w_hh, w_out, base);
    gates_gemm<<<dim3(128, 8), 256, 0, stream>>>(AB, wfull, b_ih, b_hh, comb, ugsg);
    attn_kernel<<<4096, 256, 0, stream>>>(input_t, memory, comb);
    out_gemm<<<dim3(128, 4), 256, 0, stream>>>(comb, woutB, b_out, ugsg, hidden, out);
}

// Round 14
// 193.530 us; speedup vs baseline: 1.0429x; 1.0429x over previous
//
#include <hip/hip_runtime.h>
#include <stdint.h>

#define B_N 16384
#define H_N 256
#define IN_W 258
#define GX_N 70
#define GY_N 70
#define SW_N 2
#define KK_N 25

typedef __bf16 bf16x8 __attribute__((ext_vector_type(8)));
typedef __bf16 bf16x4 __attribute__((ext_vector_type(4)));
typedef __bf16 bf16x2 __attribute__((ext_vector_type(2)));
typedef float f32x4 __attribute__((ext_vector_type(4)));
typedef float f32x2 __attribute__((ext_vector_type(2)));

#define AS1 __attribute__((address_space(1)))
#define AS3 __attribute__((address_space(3)))

static __device__ __forceinline__ void gload16(const void* g, void* l) {
    __builtin_amdgcn_global_load_lds((const AS1 uint32_t*)g, (AS3 uint32_t*)l, 16, 0, 0);
}

// ---- ws layout (bf16 elements) ----
// AB    at 0        : [16384][512]  ([feat|hid])            16 MB
// wfull at 8388608  : [1024][512]   rows j=c*256+col, c in {r,i,s,n};
//                     k<256 -> wih[base_c+col][k], k>=256 -> whh[base_c+col][k-256]
//                     base_c = {0,256,768,512}
// woutB at 8912896  : [256][512]
// comb  at 9043968  : [16384][512]  ([mix|q])               16 MB
// ugsg  at 17432576 : [16384][256][2] (ug,sg interleaved)   16 MB
#define E_AB   8388608ULL
#define E_WF   8912896ULL
#define E_WOUT 9043968ULL
#define E_COMB 9043968ULL
#define E_UGSG 17432576ULL

// 16B-store cast: each thread converts 8 f32 -> bf16x8 per iteration.
// All section boundaries and k-splits are ==0 mod 8.
__global__ __launch_bounds__(256) void cast_kernel(
    const float* __restrict__ in_t, const float* __restrict__ hid,
    const float* __restrict__ wih, const float* __restrict__ whh,
    const float* __restrict__ wout, __bf16* __restrict__ dst)
{
    size_t g = (size_t)blockIdx.x * blockDim.x + threadIdx.x;
    size_t stride = (size_t)gridDim.x * blockDim.x;
    for (size_t e = g * 8; e < E_WOUT; e += stride * 8) {
        float s[8];
        if (e < E_AB) {
            size_t row = e >> 9;
            size_t c = e & 511;
            if (c < 256) {
                const f32x2* s2 = reinterpret_cast<const f32x2*>(in_t + row * IN_W + c);
#pragma unroll
                for (int q = 0; q < 4; q++) { f32x2 a = s2[q]; s[q * 2] = a.x; s[q * 2 + 1] = a.y; }
            } else {
                const f32x4* s4 = reinterpret_cast<const f32x4*>(hid + row * 256 + (c - 256));
#pragma unroll
                for (int q = 0; q < 2; q++) { f32x4 a = s4[q]; s[q*4]=a.x; s[q*4+1]=a.y; s[q*4+2]=a.z; s[q*4+3]=a.w; }
            }
        } else if (e < E_WF) {
            size_t off = e - E_AB;
            size_t j = off >> 9;       // 0..1023
            size_t k = off & 511;
            size_t c = j >> 8;         // 0..3
            size_t col = j & 255;
            size_t base = (c == 0) ? 0 : (c == 1) ? 256 : (c == 2) ? 768 : 512;
            const float* srcm = (k < 256) ? wih : whh;
            const f32x4* s4 = reinterpret_cast<const f32x4*>(srcm + (base + col) * 256 + (k & 255));
#pragma unroll
            for (int q = 0; q < 2; q++) { f32x4 a = s4[q]; s[q*4]=a.x; s[q*4+1]=a.y; s[q*4+2]=a.z; s[q*4+3]=a.w; }
        } else {
            const f32x4* s4 = reinterpret_cast<const f32x4*>(wout + (e - E_WF));
#pragma unroll
            for (int q = 0; q < 2; q++) { f32x4 a = s4[q]; s[q*4]=a.x; s[q*4+1]=a.y; s[q*4+2]=a.z; s[q*4+3]=a.w; }
        }
        bf16x8 o;
#pragma unroll
        for (int q = 0; q < 8; q++) o[q] = (__bf16)s[q];
        *reinterpret_cast<bf16x8*>(dst + e) = o;
    }
}

// Fused gates GEMM, K=512 concat form. r6-PROVEN 2-phase dbuf pipeline
// (46-48 us, VGPR 64, no spill). Counted-vmcnt variants regressed twice
// (r3/r7) — do not retry as graft.
// block = 128 rows x 128 cols (32 hcols x 4 gates), 4 waves, wave 32x128,
// acc 20 f32x4 = 80 regs. LDS 32KB -> 4 blocks/CU (grid 1024 = 4/CU).
__global__ __launch_bounds__(256, 2) void gates_gemm(
    const __bf16* __restrict__ AB, const __bf16* __restrict__ wfull,
    const float* __restrict__ b_ih, const float* __restrict__ b_hh,
    __bf16* __restrict__ comb, __bf16* __restrict__ ugsg)
{
    __shared__ __bf16 ldsA[2][4096];   // [buf][seg(4)][row(128)][8]
    __shared__ __bf16 ldsB[2][4096];   // [buf][seg(4)][brow(128)][8]
    const int t = threadIdx.x;
    const int lane = t & 63, w = t >> 6;
    const int lr = lane & 15, seg = lane >> 4;
    const int rb = blockIdx.x * 128;
    const int h0 = blockIdx.y * 32;

    // staging: thread t owns row (t&127), k-segs {t>>7, (t>>7)+2}
    const int rA = t & 127;
    const int sA = t >> 7;             // 0..1
    const __bf16* gAt = AB + (size_t)(rb + rA) * 512 + sA * 8;
    const int bc = rA >> 5, bcol = rA & 31;  // brow -> wfull row bc*256+h0+bcol
    const __bf16* gBt = wfull + (size_t)(bc * 256 + h0 + bcol) * 512 + sA * 8;
    __bf16* lA0 = &ldsA[0][t * 8];
    __bf16* lA1 = &ldsA[1][t * 8];
    __bf16* lB0 = &ldsB[0][t * 8];
    __bf16* lB1 = &ldsB[1][t * 8];

    f32x4 acc[2][6], accni[2][2], accnh[2][2];
#pragma unroll
    for (int rh = 0; rh < 2; rh++) {
#pragma unroll
        for (int cn = 0; cn < 6; cn++) acc[rh][cn] = (f32x4){0.f, 0.f, 0.f, 0.f};
        accni[rh][0] = (f32x4){0.f, 0.f, 0.f, 0.f};
        accni[rh][1] = (f32x4){0.f, 0.f, 0.f, 0.f};
        accnh[rh][0] = (f32x4){0.f, 0.f, 0.f, 0.f};
        accnh[rh][1] = (f32x4){0.f, 0.f, 0.f, 0.f};
    }

    // prologue: stage tile 0 into buf 0
    gload16(gAt + 0, lA0);
    gload16(gAt + 16, lA0 + 2048);
    gload16(gBt + 0, lB0);
    gload16(gBt + 16, lB0 + 2048);
    __syncthreads();   // implicit vmcnt(0)

#pragma unroll 1
    for (int tt = 0; tt < 16; tt++) {
        const int cur = tt & 1;
        if (tt < 15) {   // issue next tile's stage BEFORE compute
            const int kn = (tt + 1) * 32;
            __bf16* la = cur ? lA0 : lA1;
            __bf16* lb = cur ? lB0 : lB1;
            gload16(gAt + kn, la);
            gload16(gAt + kn + 16, la + 2048);
            gload16(gBt + kn, lb);
            gload16(gBt + kn + 16, lb + 2048);
        }
        const __bf16* cA = ldsA[cur];
        const __bf16* cB = ldsB[cur];
        bf16x8 af[2];
#pragma unroll
        for (int rh = 0; rh < 2; rh++)
            af[rh] = *reinterpret_cast<const bf16x8*>(cA + seg * 1024 + (w * 32 + rh * 16 + lr) * 8);
#pragma unroll
        for (int cn = 0; cn < 6; cn++) {
            const int c = cn >> 1, hh = cn & 1;
            bf16x8 bb = *reinterpret_cast<const bf16x8*>(cB + seg * 1024 + (c * 32 + hh * 16 + lr) * 8);
#pragma unroll
            for (int rh = 0; rh < 2; rh++)
                acc[rh][(c << 1) + hh] = __builtin_amdgcn_mfma_f32_16x16x32_bf16(af[rh], bb, acc[rh][(c << 1) + hh], 0, 0, 0);
        }
        bf16x8 b6 = *reinterpret_cast<const bf16x8*>(cB + seg * 1024 + (96 + lr) * 8);
        bf16x8 b7 = *reinterpret_cast<const bf16x8*>(cB + seg * 1024 + (112 + lr) * 8);
        if (tt < 8) {
#pragma unroll
            for (int rh = 0; rh < 2; rh++) {
                accni[rh][0] = __builtin_amdgcn_mfma_f32_16x16x32_bf16(af[rh], b6, accni[rh][0], 0, 0, 0);
                accni[rh][1] = __builtin_amdgcn_mfma_f32_16x16x32_bf16(af[rh], b7, accni[rh][1], 0, 0, 0);
            }
        } else {
#pragma unroll
            for (int rh = 0; rh < 2; rh++) {
                accnh[rh][0] = __builtin_amdgcn_mfma_f32_16x16x32_bf16(af[rh], b6, accnh[rh][0], 0, 0, 0);
                accnh[rh][1] = __builtin_amdgcn_mfma_f32_16x16x32_bf16(af[rh], b7, accnh[rh][1], 0, 0, 0);
            }
        }
        __syncthreads();   // vmcnt(0): next tile landed; lgkm: reads done
    }

#pragma unroll
    for (int hh = 0; hh < 2; hh++) {
        const int col = h0 + hh * 16 + lr;
        const float br_ = b_ih[col] + b_hh[col];
        const float bi_ = b_ih[col + 256] + b_hh[col + 256];
        const float bs_ = b_ih[col + 768] + b_hh[col + 768];
        const float bni = b_ih[col + 512];
        const float bnh = b_hh[col + 512];
#pragma unroll
        for (int rh = 0; rh < 2; rh++) {
#pragma unroll
            for (int r = 0; r < 4; r++) {
                const int row = rb + w * 32 + rh * 16 + seg * 4 + r;
                float sr = acc[rh][hh][r] + br_;
                float si = acc[rh][2 + hh][r] + bi_;
                float ss = acc[rh][4 + hh][r] + bs_;
                float vni = accni[rh][hh][r] + bni;
                float vnh = accnh[rh][hh][r] + bnh;
                float rg = 1.f / (1.f + __expf(-sr));
                float ug = 1.f / (1.f + __expf(-si));
                float sg = 1.f / (1.f + __expf(-ss));
                float ng = tanhf(vni + rg * vnh);
                comb[(size_t)row * 512 + 256 + col] = (__bf16)ng;
                bf16x2 us;
                us.x = (__bf16)ug;
                us.y = (__bf16)sg;
                *reinterpret_cast<bf16x2*>(ugsg + ((size_t)row * 256 + col) * 2) = us;
            }
        }
    }
}

// DPP 64-lane sum (6 VALU adds, zero DS-pipe ops). CTRL is a template
// param (must be an integer-constant expr). bound_ctrl=true: invalid
// source lane reads 0 (sum identity).
template <int CTRL>
static __device__ __forceinline__ float dpp_add_step(float x) {
    int xi = __builtin_bit_cast(int, x);
    int sh = __builtin_amdgcn_update_dpp(0, xi, CTRL, 0xf, 0xf, true);
    return x + __builtin_bit_cast(float, sh);
}
static __device__ __forceinline__ float wave_sum_readlane(float x) {
    x = dpp_add_step<0x111>(x);  // row_shr:1
    x = dpp_add_step<0x112>(x);  // row_shr:2
    x = dpp_add_step<0x114>(x);  // row_shr:4
    x = dpp_add_step<0x118>(x);  // row_shr:8  -> lane15/31/47/63 hold row sums
    x = dpp_add_step<0x142>(x);  // row_bcast:15
    x = dpp_add_step<0x143>(x);  // row_bcast:31 -> lane63 = total
    int s = __builtin_amdgcn_readlane(__builtin_bit_cast(int, x), 63);
    return __builtin_bit_cast(float, s);
}

// Attention v3 (r11-proven, 31.8us — v4's reload variant regressed to
// 40.4, reverted): wave per row, coalesced f32x4 context loads held in
// registers (v[25], static-indexed), DPP-VALU reduction (no DS pipe),
// redundant per-lane softmax. No LDS.
__global__ __launch_bounds__(256) void attn_kernel(
    const float* __restrict__ in_t, const float* __restrict__ memory,
    __bf16* __restrict__ comb)
{
    const int w = threadIdx.x >> 6;
    const int lane = threadIdx.x & 63;
    const int b = blockIdx.x * 4 + w;
    const float* row_in = in_t + (size_t)b * IN_W;
    int gx = (int)row_in[256] + SW_N;
    int gy = (int)row_in[257] + SW_N;
    gx = min(max(gx, 0), GX_N - 1);
    gy = min(max(gy, 0), GY_N - 1);

    int xs[5], ys[5];
#pragma unroll
    for (int d = 0; d < 5; d++) {
        xs[d] = min(max(gx + d - SW_N, 0), GX_N - 1);
        ys[d] = min(max(gy + d - SW_N, 0), GY_N - 1);
    }

    bf16x4 qb = *reinterpret_cast<const bf16x4*>(comb + (size_t)b * 512 + 256 + lane * 4);
    const float q0 = (float)qb.x, q1 = (float)qb.y, q2 = (float)qb.z, q3 = (float)qb.w;

    f32x4 v[KK_N];
    float sc[KK_N];
#pragma unroll
    for (int k = 0; k < KK_N; k++) {       // full unroll: v[],sc[] static-indexed
        const int i = k / 5, j = k % 5;    // compile-time
        const f32x4* cp = reinterpret_cast<const f32x4*>(
            memory + ((size_t)xs[i] * GY_N + ys[j]) * H_N);
        v[k] = cp[lane];                   // coalesced 1KB/wave
        float p = q0 * v[k].x + q1 * v[k].y + q2 * v[k].z + q3 * v[k].w;
        sc[k] = wave_sum_readlane(p);      // 6 VALU-DPP + readlane, no DS
    }

    // softmax over 25 uniform scores (ref: attn==0 -> -inf mask; all-masked -> 0)
#pragma unroll
    for (int k = 0; k < KK_N; k++) sc[k] = (sc[k] == 0.f) ? -INFINITY : sc[k];
    float mx = -INFINITY;
#pragma unroll
    for (int k = 0; k < KK_N; k++) mx = fmaxf(mx, sc[k]);
    float d = 0.f;
    if (mx > -INFINITY) {
#pragma unroll
        for (int k = 0; k < KK_N; k++) { sc[k] = __expf(sc[k] - mx); d += sc[k]; }
    } else {
#pragma unroll
        for (int k = 0; k < KK_N; k++) sc[k] = 0.f;
    }
    const float inv = (d != 0.f) ? 1.f / d : 0.f;

    f32x4 o = (f32x4){0.f, 0.f, 0.f, 0.f};
#pragma unroll
    for (int k = 0; k < KK_N; k++) {
        const float wk = sc[k] * inv;
        o.x += wk * v[k].x; o.y += wk * v[k].y; o.z += wk * v[k].z; o.w += wk * v[k].w;
    }
    bf16x4 ob;
    ob.x = (__bf16)o.x; ob.y = (__bf16)o.y; ob.z = (__bf16)o.z; ob.w = (__bf16)o.w;
    *reinterpret_cast<bf16x4*>(comb + (size_t)b * 512 + lane * 4) = ob;
}

// Output GEMM (K=512) + tanh + final blend. 2-phase dbuf on a 64x64
// tile: grid (256,4) = 1024 blocks = 4 blocks/CU (was 2/CU at 128x64) —
// the same blocks/CU lever that fixed gates in r6 (m114 cross-block
// overlap hides the per-step barrier drain). LDS 16KB (2 x (4KB A +
// 4KB B)); wave = 16 rows x 64 cols, acc 4 f32x4 = 16 regs, (256,4)
// VGPR cap 64 safe. Per wave-step: 5 ds_read, 4 MFMA; 2 gload16/thread.
__global__ __launch_bounds__(256, 4) void out_gemm(
    const __bf16* __restrict__ comb, const __bf16* __restrict__ woB,
    const float* __restrict__ b_out, const __bf16* __restrict__ ugsg,
    const float* __restrict__ hidden, float* __restrict__ out)
{
    __shared__ __bf16 ldsA[2][2048];   // [buf][seg(4)][row(64)][8]
    __shared__ __bf16 ldsB[2][2048];   // [buf][seg(4)][brow(64)][8]
    const int t = threadIdx.x;
    const int lane = t & 63, w = t >> 6;
    const int lr = lane & 15, seg = lane >> 4;
    const int rb = blockIdx.x * 64;
    const int n0 = blockIdx.y * 64;

    // staging: thread t owns row (t&63), k-seg (t>>6); 1 gload16 each for A,B
    const __bf16* gAt = comb + (size_t)(rb + (t & 63)) * 512 + ((t >> 6) << 3);
    const __bf16* gBt = woB + (size_t)(n0 + (t & 63)) * 512 + ((t >> 6) << 3);
    __bf16* lA0 = &ldsA[0][t * 8];
    __bf16* lA1 = &ldsA[1][t * 8];
    __bf16* lB0 = &ldsB[0][t * 8];
    __bf16* lB1 = &ldsB[1][t * 8];

    f32x4 acc[4];
#pragma unroll
    for (int ct = 0; ct < 4; ct++) acc[ct] = (f32x4){0.f, 0.f, 0.f, 0.f};

    // prologue: tile 0 -> buf 0
    gload16(gAt + 0, lA0);
    gload16(gBt + 0, lB0);
    __syncthreads();

#pragma unroll 1
    for (int tt = 0; tt < 16; tt++) {
        const int cur = tt & 1;
        if (tt < 15) {
            const int kn = (tt + 1) * 32;
            gload16(gAt + kn, cur ? lA0 : lA1);
            gload16(gBt + kn, cur ? lB0 : lB1);
        }
        const __bf16* cA = ldsA[cur];
        const __bf16* cB = ldsB[cur];
        bf16x8 af = *reinterpret_cast<const bf16x8*>(cA + seg * 512 + (w * 16 + lr) * 8);
#pragma unroll
        for (int ct = 0; ct < 4; ct++) {
            bf16x8 bb = *reinterpret_cast<const bf16x8*>(cB + seg * 512 + (ct * 16 + lr) * 8);
            acc[ct] = __builtin_amdgcn_mfma_f32_16x16x32_bf16(af, bb, acc[ct], 0, 0, 0);
        }
        __syncthreads();
    }

#pragma unroll
    for (int ct = 0; ct < 4; ct++) {
        int col = n0 + ct * 16 + lr;
        float bo = b_out[col];
#pragma unroll
        for (int r = 0; r < 4; r++) {
            int row = rb + w * 16 + seg * 4 + r;
            size_t idx = (size_t)row * 256 + col;
            float acs = tanhf(acc[ct][r] + bo);
            float ng = (float)comb[(size_t)row * 512 + 256 + col];
            bf16x2 us = *reinterpret_cast<const bf16x2*>(ugsg + idx * 2);
            float ug = (float)us.x, sg = (float)us.y;
            float curr = ng + sg * acs;
            out[idx] = curr + ug * (hidden[idx] - curr);
        }
    }
}

extern "C" void kernel_launch(void* const* d_in, const int* in_sizes, int n_in,
                              void* d_out, int out_size, void* d_ws, size_t ws_size,
                              hipStream_t stream) {
    const float* input_t = (const float*)d_in[0];
    const float* hidden  = (const float*)d_in[1];
    const float* w_ih    = (const float*)d_in[2];
    const float* b_ih    = (const float*)d_in[3];
    const float* w_hh    = (const float*)d_in[4];
    const float* b_hh    = (const float*)d_in[5];
    const float* w_out   = (const float*)d_in[6];
    const float* b_out   = (const float*)d_in[7];
    const float* memory  = (const float*)d_in[8];
    float* out = (float*)d_out;

    __bf16* base  = (__bf16*)d_ws;
    __bf16* AB    = base;
    __bf16* wfull = base + E_AB;
    __bf16* woutB = base + E_WF;
    __bf16* comb  = base + E_COMB;
    __bf16* ugsg  = base + E_UGSG;

    cast_kernel<<<4096, 256, 0, stream>>>(input_t, hidden, w_ih, w_hh, w_out, base);
    gates_gemm<<<dim3(128, 8), 256, 0, stream>>>(AB, wfull, b_ih, b_hh, comb, ugsg);
    attn_kernel<<<4096, 256, 0, stream>>>(input_t, memory, comb);
    out_gemm<<<dim3(256, 4), 256, 0, stream>>>(comb, woutB, b_out, ugsg, hidden, out);
}

// Round 15
// 190.345 us; speedup vs baseline: 1.0604x; 1.0167x over previous
//
#include <hip/hip_runtime.h>
#include <stdint.h>

#define B_N 16384
#define H_N 256
#define IN_W 258
#define GX_N 70
#define GY_N 70
#define SW_N 2
#define KK_N 25

typedef __bf16 bf16x8 __attribute__((ext_vector_type(8)));
typedef __bf16 bf16x4 __attribute__((ext_vector_type(4)));
typedef __bf16 bf16x2 __attribute__((ext_vector_type(2)));
typedef float f32x4 __attribute__((ext_vector_type(4)));
typedef float f32x2 __attribute__((ext_vector_type(2)));

#define AS1 __attribute__((address_space(1)))
#define AS3 __attribute__((address_space(3)))

static __device__ __forceinline__ void gload16(const void* g, void* l) {
    __builtin_amdgcn_global_load_lds((const AS1 uint32_t*)g, (AS3 uint32_t*)l, 16, 0, 0);
}

// ---- ws layout (bf16 elements) ----
// AB    at 0        : [16384][512]  ([feat|hid])            16 MB
// wfull at 8388608  : [1024][512]   rows j=c*256+col, c in {r,i,s,n};
//                     k<256 -> wih[base_c+col][k], k>=256 -> whh[base_c+col][k-256]
//                     base_c = {0,256,768,512}
// woutB at 8912896  : [256][512]
// comb  at 9043968  : [16384][512]  ([mix|q])               16 MB
// ugsg  at 17432576 : [16384][256][2] (ug,sg interleaved)   16 MB
#define E_AB   8388608ULL
#define E_WF   8912896ULL
#define E_WOUT 9043968ULL
#define E_COMB 9043968ULL
#define E_UGSG 17432576ULL

// 16B-store cast: each thread converts 8 f32 -> bf16x8 per iteration.
// All section boundaries and k-splits are ==0 mod 8.
__global__ __launch_bounds__(256) void cast_kernel(
    const float* __restrict__ in_t, const float* __restrict__ hid,
    const float* __restrict__ wih, const float* __restrict__ whh,
    const float* __restrict__ wout, __bf16* __restrict__ dst)
{
    size_t g = (size_t)blockIdx.x * blockDim.x + threadIdx.x;
    size_t stride = (size_t)gridDim.x * blockDim.x;
    for (size_t e = g * 8; e < E_WOUT; e += stride * 8) {
        float s[8];
        if (e < E_AB) {
            size_t row = e >> 9;
            size_t c = e & 511;
            if (c < 256) {
                const f32x2* s2 = reinterpret_cast<const f32x2*>(in_t + row * IN_W + c);
#pragma unroll
                for (int q = 0; q < 4; q++) { f32x2 a = s2[q]; s[q * 2] = a.x; s[q * 2 + 1] = a.y; }
            } else {
                const f32x4* s4 = reinterpret_cast<const f32x4*>(hid + row * 256 + (c - 256));
#pragma unroll
                for (int q = 0; q < 2; q++) { f32x4 a = s4[q]; s[q*4]=a.x; s[q*4+1]=a.y; s[q*4+2]=a.z; s[q*4+3]=a.w; }
            }
        } else if (e < E_WF) {
            size_t off = e - E_AB;
            size_t j = off >> 9;       // 0..1023
            size_t k = off & 511;
            size_t c = j >> 8;         // 0..3
            size_t col = j & 255;
            size_t base = (c == 0) ? 0 : (c == 1) ? 256 : (c == 2) ? 768 : 512;
            const float* srcm = (k < 256) ? wih : whh;
            const f32x4* s4 = reinterpret_cast<const f32x4*>(srcm + (base + col) * 256 + (k & 255));
#pragma unroll
            for (int q = 0; q < 2; q++) { f32x4 a = s4[q]; s[q*4]=a.x; s[q*4+1]=a.y; s[q*4+2]=a.z; s[q*4+3]=a.w; }
        } else {
            const f32x4* s4 = reinterpret_cast<const f32x4*>(wout + (e - E_WF));
#pragma unroll
            for (int q = 0; q < 2; q++) { f32x4 a = s4[q]; s[q*4]=a.x; s[q*4+1]=a.y; s[q*4+2]=a.z; s[q*4+3]=a.w; }
        }
        bf16x8 o;
#pragma unroll
        for (int q = 0; q < 8; q++) o[q] = (__bf16)s[q];
        *reinterpret_cast<bf16x8*>(dst + e) = o;
    }
}

// Fused gates GEMM, K=512 concat form. r6-PROVEN 2-phase dbuf pipeline
// (46-48 us, VGPR 64, no spill). Counted-vmcnt variants regressed twice
// (r3/r7) — do not retry as graft.
// block = 128 rows x 128 cols (32 hcols x 4 gates), 4 waves, wave 32x128,
// acc 20 f32x4 = 80 regs. LDS 32KB -> 4 blocks/CU (grid 1024 = 4/CU).
__global__ __launch_bounds__(256, 2) void gates_gemm(
    const __bf16* __restrict__ AB, const __bf16* __restrict__ wfull,
    const float* __restrict__ b_ih, const float* __restrict__ b_hh,
    __bf16* __restrict__ comb, __bf16* __restrict__ ugsg)
{
    __shared__ __bf16 ldsA[2][4096];   // [buf][seg(4)][row(128)][8]
    __shared__ __bf16 ldsB[2][4096];   // [buf][seg(4)][brow(128)][8]
    const int t = threadIdx.x;
    const int lane = t & 63, w = t >> 6;
    const int lr = lane & 15, seg = lane >> 4;
    const int rb = blockIdx.x * 128;
    const int h0 = blockIdx.y * 32;

    // staging: thread t owns row (t&127), k-segs {t>>7, (t>>7)+2}
    const int rA = t & 127;
    const int sA = t >> 7;             // 0..1
    const __bf16* gAt = AB + (size_t)(rb + rA) * 512 + sA * 8;
    const int bc = rA >> 5, bcol = rA & 31;  // brow -> wfull row bc*256+h0+bcol
    const __bf16* gBt = wfull + (size_t)(bc * 256 + h0 + bcol) * 512 + sA * 8;
    __bf16* lA0 = &ldsA[0][t * 8];
    __bf16* lA1 = &ldsA[1][t * 8];
    __bf16* lB0 = &ldsB[0][t * 8];
    __bf16* lB1 = &ldsB[1][t * 8];

    f32x4 acc[2][6], accni[2][2], accnh[2][2];
#pragma unroll
    for (int rh = 0; rh < 2; rh++) {
#pragma unroll
        for (int cn = 0; cn < 6; cn++) acc[rh][cn] = (f32x4){0.f, 0.f, 0.f, 0.f};
        accni[rh][0] = (f32x4){0.f, 0.f, 0.f, 0.f};
        accni[rh][1] = (f32x4){0.f, 0.f, 0.f, 0.f};
        accnh[rh][0] = (f32x4){0.f, 0.f, 0.f, 0.f};
        accnh[rh][1] = (f32x4){0.f, 0.f, 0.f, 0.f};
    }

    // prologue: stage tile 0 into buf 0
    gload16(gAt + 0, lA0);
    gload16(gAt + 16, lA0 + 2048);
    gload16(gBt + 0, lB0);
    gload16(gBt + 16, lB0 + 2048);
    __syncthreads();   // implicit vmcnt(0)

#pragma unroll 1
    for (int tt = 0; tt < 16; tt++) {
        const int cur = tt & 1;
        if (tt < 15) {   // issue next tile's stage BEFORE compute
            const int kn = (tt + 1) * 32;
            __bf16* la = cur ? lA0 : lA1;
            __bf16* lb = cur ? lB0 : lB1;
            gload16(gAt + kn, la);
            gload16(gAt + kn + 16, la + 2048);
            gload16(gBt + kn, lb);
            gload16(gBt + kn + 16, lb + 2048);
        }
        const __bf16* cA = ldsA[cur];
        const __bf16* cB = ldsB[cur];
        bf16x8 af[2];
#pragma unroll
        for (int rh = 0; rh < 2; rh++)
            af[rh] = *reinterpret_cast<const bf16x8*>(cA + seg * 1024 + (w * 32 + rh * 16 + lr) * 8);
#pragma unroll
        for (int cn = 0; cn < 6; cn++) {
            const int c = cn >> 1, hh = cn & 1;
            bf16x8 bb = *reinterpret_cast<const bf16x8*>(cB + seg * 1024 + (c * 32 + hh * 16 + lr) * 8);
#pragma unroll
            for (int rh = 0; rh < 2; rh++)
                acc[rh][(c << 1) + hh] = __builtin_amdgcn_mfma_f32_16x16x32_bf16(af[rh], bb, acc[rh][(c << 1) + hh], 0, 0, 0);
        }
        bf16x8 b6 = *reinterpret_cast<const bf16x8*>(cB + seg * 1024 + (96 + lr) * 8);
        bf16x8 b7 = *reinterpret_cast<const bf16x8*>(cB + seg * 1024 + (112 + lr) * 8);
        if (tt < 8) {
#pragma unroll
            for (int rh = 0; rh < 2; rh++) {
                accni[rh][0] = __builtin_amdgcn_mfma_f32_16x16x32_bf16(af[rh], b6, accni[rh][0], 0, 0, 0);
                accni[rh][1] = __builtin_amdgcn_mfma_f32_16x16x32_bf16(af[rh], b7, accni[rh][1], 0, 0, 0);
            }
        } else {
#pragma unroll
            for (int rh = 0; rh < 2; rh++) {
                accnh[rh][0] = __builtin_amdgcn_mfma_f32_16x16x32_bf16(af[rh], b6, accnh[rh][0], 0, 0, 0);
                accnh[rh][1] = __builtin_amdgcn_mfma_f32_16x16x32_bf16(af[rh], b7, accnh[rh][1], 0, 0, 0);
            }
        }
        __syncthreads();   // vmcnt(0): next tile landed; lgkm: reads done
    }

#pragma unroll
    for (int hh = 0; hh < 2; hh++) {
        const int col = h0 + hh * 16 + lr;
        const float br_ = b_ih[col] + b_hh[col];
        const float bi_ = b_ih[col + 256] + b_hh[col + 256];
        const float bs_ = b_ih[col + 768] + b_hh[col + 768];
        const float bni = b_ih[col + 512];
        const float bnh = b_hh[col + 512];
#pragma unroll
        for (int rh = 0; rh < 2; rh++) {
#pragma unroll
            for (int r = 0; r < 4; r++) {
                const int row = rb + w * 32 + rh * 16 + seg * 4 + r;
                float sr = acc[rh][hh][r] + br_;
                float si = acc[rh][2 + hh][r] + bi_;
                float ss = acc[rh][4 + hh][r] + bs_;
                float vni = accni[rh][hh][r] + bni;
                float vnh = accnh[rh][hh][r] + bnh;
                float rg = 1.f / (1.f + __expf(-sr));
                float ug = 1.f / (1.f + __expf(-si));
                float sg = 1.f / (1.f + __expf(-ss));
                float ng = tanhf(vni + rg * vnh);
                comb[(size_t)row * 512 + 256 + col] = (__bf16)ng;
                bf16x2 us;
                us.x = (__bf16)ug;
                us.y = (__bf16)sg;
                *reinterpret_cast<bf16x2*>(ugsg + ((size_t)row * 256 + col) * 2) = us;
            }
        }
    }
}

// DPP 64-lane sum (6 VALU adds, zero DS-pipe ops). CTRL is a template
// param (must be an integer-constant expr). bound_ctrl=true: invalid
// source lane reads 0 (sum identity).
template <int CTRL>
static __device__ __forceinline__ float dpp_add_step(float x) {
    int xi = __builtin_bit_cast(int, x);
    int sh = __builtin_amdgcn_update_dpp(0, xi, CTRL, 0xf, 0xf, true);
    return x + __builtin_bit_cast(float, sh);
}
static __device__ __forceinline__ float wave_sum_readlane(float x) {
    x = dpp_add_step<0x111>(x);  // row_shr:1
    x = dpp_add_step<0x112>(x);  // row_shr:2
    x = dpp_add_step<0x114>(x);  // row_shr:4
    x = dpp_add_step<0x118>(x);  // row_shr:8  -> lane15/31/47/63 hold row sums
    x = dpp_add_step<0x142>(x);  // row_bcast:15
    x = dpp_add_step<0x143>(x);  // row_bcast:31 -> lane63 = total
    int s = __builtin_amdgcn_readlane(__builtin_bit_cast(int, x), 63);
    return __builtin_bit_cast(float, s);
}

// Attention v3 (r11-proven, 31.8us): wave per row, coalesced f32x4
// context loads held in registers (v[25], static-indexed), DPP-VALU
// reduction (no DS pipe), redundant per-lane softmax. No LDS.
__global__ __launch_bounds__(256) void attn_kernel(
    const float* __restrict__ in_t, const float* __restrict__ memory,
    __bf16* __restrict__ comb)
{
    const int w = threadIdx.x >> 6;
    const int lane = threadIdx.x & 63;
    const int b = blockIdx.x * 4 + w;
    const float* row_in = in_t + (size_t)b * IN_W;
    int gx = (int)row_in[256] + SW_N;
    int gy = (int)row_in[257] + SW_N;
    gx = min(max(gx, 0), GX_N - 1);
    gy = min(max(gy, 0), GY_N - 1);

    int xs[5], ys[5];
#pragma unroll
    for (int d = 0; d < 5; d++) {
        xs[d] = min(max(gx + d - SW_N, 0), GX_N - 1);
        ys[d] = min(max(gy + d - SW_N, 0), GY_N - 1);
    }

    bf16x4 qb = *reinterpret_cast<const bf16x4*>(comb + (size_t)b * 512 + 256 + lane * 4);
    const float q0 = (float)qb.x, q1 = (float)qb.y, q2 = (float)qb.z, q3 = (float)qb.w;

    f32x4 v[KK_N];
    float sc[KK_N];
#pragma unroll
    for (int k = 0; k < KK_N; k++) {       // full unroll: v[],sc[] static-indexed
        const int i = k / 5, j = k % 5;    // compile-time
        const f32x4* cp = reinterpret_cast<const f32x4*>(
            memory + ((size_t)xs[i] * GY_N + ys[j]) * H_N);
        v[k] = cp[lane];                   // coalesced 1KB/wave
        float p = q0 * v[k].x + q1 * v[k].y + q2 * v[k].z + q3 * v[k].w;
        sc[k] = wave_sum_readlane(p);      // 6 VALU-DPP + readlane, no DS
    }

    // softmax over 25 uniform scores (ref: attn==0 -> -inf mask; all-masked -> 0)
#pragma unroll
    for (int k = 0; k < KK_N; k++) sc[k] = (sc[k] == 0.f) ? -INFINITY : sc[k];
    float mx = -INFINITY;
#pragma unroll
    for (int k = 0; k < KK_N; k++) mx = fmaxf(mx, sc[k]);
    float d = 0.f;
    if (mx > -INFINITY) {
#pragma unroll
        for (int k = 0; k < KK_N; k++) { sc[k] = __expf(sc[k] - mx); d += sc[k]; }
    } else {
#pragma unroll
        for (int k = 0; k < KK_N; k++) sc[k] = 0.f;
    }
    const float inv = (d != 0.f) ? 1.f / d : 0.f;

    f32x4 o = (f32x4){0.f, 0.f, 0.f, 0.f};
#pragma unroll
    for (int k = 0; k < KK_N; k++) {
        const float wk = sc[k] * inv;
        o.x += wk * v[k].x; o.y += wk * v[k].y; o.z += wk * v[k].z; o.w += wk * v[k].w;
    }
    bf16x4 ob;
    ob.x = (__bf16)o.x; ob.y = (__bf16)o.y; ob.z = (__bf16)o.z; ob.w = (__bf16)o.w;
    *reinterpret_cast<bf16x4*>(comb + (size_t)b * 512 + lane * 4) = ob;
}

// Output GEMM (K=512) + tanh + final blend. BK=64: 8 K-steps instead of
// 16 — the step-count theory: all 16-step variants cost ~45us because
// per-step drain latency dominates (3 structures, identical bucket);
// halving the steps halves the drain count. Tile 64x64, 2-phase dbuf,
// LDS [buf][kb(2)][seg(4)][row(64)][8] = 2x(8+8)KB = 32KB -> 4 blocks/CU
// at (256,4) (acc 16 + af 8 regs, cap 64 safe).
// Staging: thread t owns row (t&63), kseg (t>>6); chunks k=kseg*8 and
// k=32+kseg*8 -> dest t*8 and t*8+2048 (wave-uniform base + lane*16B ok).
// Per wave-step: 10 ds_read_b128, 8 MFMA.
__global__ __launch_bounds__(256, 4) void out_gemm(
    const __bf16* __restrict__ comb, const __bf16* __restrict__ woB,
    const float* __restrict__ b_out, const __bf16* __restrict__ ugsg,
    const float* __restrict__ hidden, float* __restrict__ out)
{
    __shared__ __bf16 ldsA[2][4096];   // [buf][kb(2)][seg(4)][row(64)][8]
    __shared__ __bf16 ldsB[2][4096];
    const int t = threadIdx.x;
    const int lane = t & 63, w = t >> 6;
    const int lr = lane & 15, seg = lane >> 4;
    const int rb = blockIdx.x * 64;
    const int n0 = blockIdx.y * 64;

    const __bf16* gAt = comb + (size_t)(rb + (t & 63)) * 512 + ((t >> 6) << 3);
    const __bf16* gBt = woB + (size_t)(n0 + (t & 63)) * 512 + ((t >> 6) << 3);
    __bf16* lA0 = &ldsA[0][t * 8];
    __bf16* lA1 = &ldsA[1][t * 8];
    __bf16* lB0 = &ldsB[0][t * 8];
    __bf16* lB1 = &ldsB[1][t * 8];

    f32x4 acc[4];
#pragma unroll
    for (int ct = 0; ct < 4; ct++) acc[ct] = (f32x4){0.f, 0.f, 0.f, 0.f};

    // prologue: tile 0 (k 0..63) -> buf 0
    gload16(gAt + 0, lA0);
    gload16(gAt + 32, lA0 + 2048);
    gload16(gBt + 0, lB0);
    gload16(gBt + 32, lB0 + 2048);
    __syncthreads();

#pragma unroll 1
    for (int tt = 0; tt < 8; tt++) {
        const int cur = tt & 1;
        if (tt < 7) {
            const int kn = (tt + 1) * 64;
            __bf16* la = cur ? lA0 : lA1;
            __bf16* lb = cur ? lB0 : lB1;
            gload16(gAt + kn, la);
            gload16(gAt + kn + 32, la + 2048);
            gload16(gBt + kn, lb);
            gload16(gBt + kn + 32, lb + 2048);
        }
        const __bf16* cA = ldsA[cur];
        const __bf16* cB = ldsB[cur];
        bf16x8 af[2];
#pragma unroll
        for (int kb = 0; kb < 2; kb++)
            af[kb] = *reinterpret_cast<const bf16x8*>(cA + kb * 2048 + seg * 512 + (w * 16 + lr) * 8);
#pragma unroll
        for (int ct = 0; ct < 4; ct++) {
#pragma unroll
            for (int kb = 0; kb < 2; kb++) {
                bf16x8 bb = *reinterpret_cast<const bf16x8*>(cB + kb * 2048 + seg * 512 + (ct * 16 + lr) * 8);
                acc[ct] = __builtin_amdgcn_mfma_f32_16x16x32_bf16(af[kb], bb, acc[ct], 0, 0, 0);
            }
        }
        __syncthreads();
    }

#pragma unroll
    for (int ct = 0; ct < 4; ct++) {
        int col = n0 + ct * 16 + lr;
        float bo = b_out[col];
#pragma unroll
        for (int r = 0; r < 4; r++) {
            int row = rb + w * 16 + seg * 4 + r;
            size_t idx = (size_t)row * 256 + col;
            float acs = tanhf(acc[ct][r] + bo);
            float ng = (float)comb[(size_t)row * 512 + 256 + col];
            bf16x2 us = *reinterpret_cast<const bf16x2*>(ugsg + idx * 2);
            float ug = (float)us.x, sg = (float)us.y;
            float curr = ng + sg * acs;
            out[idx] = curr + ug * (hidden[idx] - curr);
        }
    }
}

extern "C" void kernel_launch(void* const* d_in, const int* in_sizes, int n_in,
                              void* d_out, int out_size, void* d_ws, size_t ws_size,
                              hipStream_t stream) {
    const float* input_t = (const float*)d_in[0];
    const float* hidden  = (const float*)d_in[1];
    const float* w_ih    = (const float*)d_in[2];
    const float* b_ih    = (const float*)d_in[3];
    const float* w_hh    = (const float*)d_in[4];
    const float* b_hh    = (const float*)d_in[5];
    const float* w_out   = (const float*)d_in[6];
    const float* b_out   = (const float*)d_in[7];
    const float* memory  = (const float*)d_in[8];
    float* out = (float*)d_out;

    __bf16* base  = (__bf16*)d_ws;
    __bf16* AB    = base;
    __bf16* wfull = base + E_AB;
    __bf16* woutB = base + E_WF;
    __bf16* comb  = base + E_COMB;
    __bf16* ugsg  = base + E_UGSG;

    cast_kernel<<<4096, 256, 0, stream>>>(input_t, hidden, w_ih, w_hh, w_out, base);
    gates_gemm<<<dim3(128, 8), 256, 0, stream>>>(AB, wfull, b_ih, b_hh, comb, ugsg);
    attn_kernel<<<4096, 256, 0, stream>>>(input_t, memory, comb);
    out_gemm<<<dim3(256, 4), 256, 0, stream>>>(comb, woutB, b_out, ugsg, hidden, out);
}